// Round 8
// baseline (114.472 us; speedup 1.0000x reference)
//
#include <hip/hip_runtime.h>
#include <hip/hip_fp16.h>
#include <hip/hip_cooperative_groups.h>

namespace cg = cooperative_groups;

#define NUM_CAMS 6
#define C_FEAT   64
#define HF       16
#define WF       44
#define NPTS     (128*128*8)   // 131072
#define FEAT_ELEMS (NUM_CAMS*C_FEAT*HF*WF)  // 270336

// ======================= cooperative single-kernel path =======================
#define CO_PPB      128
#define CO_NTHREADS 1024
#define CO_NBLOCKS  256        // 1 block/CU -> co-residency guaranteed
#define CO_NCHUNKS  (NPTS / (CO_PPB * CO_NBLOCKS))   // 4

// packed per (point,cam) sampling params: 16 B -> one ds_read_b128
struct alignas(16) PCP {
    __half   w00, w10, w01, w11;  // bilinear weights (0 for OOB corner/invalid)
    int      base;                // half-elem offset of (cam,y0,x0) pixel
    unsigned flags;               // dx | (dy<<16) | (valid<<31)
};

__global__ __launch_bounds__(CO_NTHREADS, 1) void uvt_all(
    const float* __restrict__ in,       // img_feats (6,64,16,44)
    const float* __restrict__ ego2cam,  // (6,4,4)
    const float* __restrict__ cam2img,  // (6,4,4)
    const float* __restrict__ vox,      // (3, NPTS)
    __half* __restrict__ featsT,        // ws: (6,16,44,64) fp16
    float* __restrict__ projws,         // ws: (6,3,4)
    float* __restrict__ out)            // (64, NPTS)
{
    const int tid = threadIdx.x;
    const int blk = blockIdx.x;

    // ---- stage A: transpose+fp16 convert, spread over the whole grid ----
    for (int g = blk * CO_NTHREADS + tid; g < FEAT_ELEMS; g += CO_NBLOCKS * CO_NTHREADS) {
        const int c   = g & 63;
        const int pix = g >> 6;
        const int x   = pix % WF;
        const int t2  = pix / WF;
        const int y   = t2 % HF;
        const int n   = t2 / HF;
        featsT[g] = __float2half(in[((n * C_FEAT + c) * HF + y) * WF + x]);
    }
    if (blk == 0 && tid < NUM_CAMS * 12) {   // proj = cam2img @ ego2cam (rows 0..2)
        const int cam = tid / 12, e = tid - cam * 12;
        const int i = e >> 2, j = e & 3;
        const float* A = cam2img + cam * 16;
        const float* B = ego2cam + cam * 16;
        float s = 0.f;
        #pragma unroll
        for (int k = 0; k < 4; ++k) s += A[i*4 + k] * B[k*4 + j];
        projws[cam * 12 + e] = s;
    }
    __threadfence();
    cg::this_grid().sync();

    // ---- LDS: union of phase-1/2 params and phase-3 staging ----
    __shared__ __align__(16) char ldsbuf[CO_PPB * (C_FEAT + 1) * sizeof(float)]; // 33280 B
    PCP   (*s_pc)[CO_PPB]       = (PCP (*)[CO_PPB])ldsbuf;       // 12288 B
    float (*s_out)[C_FEAT + 1]  = (float (*)[C_FEAT + 1])ldsbuf; // 33280 B

    for (int chunk = 0; chunk < CO_NCHUNKS; ++chunk) {
        const int p0 = (chunk * CO_NBLOCKS + blk) * CO_PPB;

        // ---- phase 1: per (point,cam) params; cam wave-uniform ----
        if (tid < NUM_CAMS * CO_PPB) {       // 768 threads, cam uniform per wave
            const int cam = __builtin_amdgcn_readfirstlane(tid >> 7);
            const int lp  = tid & (CO_PPB - 1);
            const int p   = p0 + lp;
            const float* M = projws + cam * 12;

            const float px = vox[p];
            const float py = vox[NPTS + p];
            const float pz = vox[2 * NPTS + p];
            const float ud = M[0]*px + M[1]*py + M[2]*pz  + M[3];
            const float vd = M[4]*px + M[5]*py + M[6]*pz  + M[7];
            const float d  = M[8]*px + M[9]*py + M[10]*pz + M[11];
            const float id = 1.0f / (d + 1e-6f);
            const float u  = ud * id;
            const float v  = vd * id;
            const bool valid = (d > 0.1f) && (u >= 0.f) && (u <= 703.f)
                                          && (v >= 0.f) && (v <= 255.f);
            PCP pc;
            if (valid) {
                const float x  = u * 0.0625f;
                const float y  = v * 0.0625f;
                const float xf = floorf(x), yf = floorf(y);
                const int   x0 = (int)xf,   y0 = (int)yf;
                const float wx1 = x - xf,  wy1 = y - yf;
                const float wx0 = 1.f - wx1, wy0 = 1.f - wy1;
                const bool bx = (x0 < WF - 1);
                const bool by = (y0 < HF - 1);
                pc.w00 = __float2half(wx0 * wy0);
                pc.w10 = __float2half(bx ? wx1 * wy0 : 0.f);
                pc.w01 = __float2half(by ? wx0 * wy1 : 0.f);
                pc.w11 = __float2half((bx && by) ? wx1 * wy1 : 0.f);
                pc.base  = ((cam * HF + y0) * WF + x0) << 6;
                pc.flags = 64u | ((unsigned)(WF * C_FEAT) << 16) | 0x80000000u;
                if (!bx) pc.flags &= ~0xFFFFu;
                if (!by) pc.flags &= ~0x7FFF0000u;
            } else {
                pc.w00 = pc.w10 = pc.w01 = pc.w11 = __float2half(0.f);
                pc.base = 0; pc.flags = 0u;
            }
            s_pc[cam][lp] = pc;
        }
        __syncthreads();

        // ---- phase 2: gated packed-half gather; oct = 8 channels (16 B) ----
        const int oct = tid & 7;
        const int pl  = tid >> 3;
        float acc[8];
        #pragma unroll
        for (int j = 0; j < 8; ++j) acc[j] = 0.f;
        int cnt = 0;

        #pragma unroll
        for (int cam = 0; cam < NUM_CAMS; ++cam) {
            const PCP pc = s_pc[cam][pl];          // one ds_read_b128
            const unsigned fl = pc.flags;
            cnt += (int)(fl >> 31);
            if (fl >> 31) {                        // exec-masked
                const int dx = (int)(fl & 0xFFFFu);
                const int dy = (int)((fl >> 16) & 0x7FFFu);
                const __half* b = featsT + pc.base + (oct << 3);
                const uint4 r00 = *(const uint4*)(b);
                const uint4 r10 = *(const uint4*)(b + dx);
                const uint4 r01 = *(const uint4*)(b + dy);
                const uint4 r11 = *(const uint4*)(b + dx + dy);
                const __half2 w00 = __half2half2(pc.w00);
                const __half2 w10 = __half2half2(pc.w10);
                const __half2 w01 = __half2half2(pc.w01);
                const __half2 w11 = __half2half2(pc.w11);
                #define BC(u_) __builtin_bit_cast(__half2, u_)
                const uint rr00[4] = {r00.x, r00.y, r00.z, r00.w};
                const uint rr10[4] = {r10.x, r10.y, r10.z, r10.w};
                const uint rr01[4] = {r01.x, r01.y, r01.z, r01.w};
                const uint rr11[4] = {r11.x, r11.y, r11.z, r11.w};
                #pragma unroll
                for (int j = 0; j < 4; ++j) {
                    __half2 s = __hmul2(w00, BC(rr00[j]));
                    s = __hfma2(w10, BC(rr10[j]), s);
                    s = __hfma2(w01, BC(rr01[j]), s);
                    s = __hfma2(w11, BC(rr11[j]), s);
                    const float2 f = __half22float2(s);
                    acc[2*j]   += f.x;
                    acc[2*j+1] += f.y;
                }
                #undef BC
            }
        }
        __syncthreads();   // all s_pc reads done before s_out overwrites union

        // ---- phase 3: transpose through LDS, 256 B-coalesced stores ----
        const float inv = 1.0f / (float)(cnt > 0 ? cnt : 1);
        const int cb = oct << 3;
        #pragma unroll
        for (int j = 0; j < 8; ++j) s_out[pl][cb + j] = acc[j] * inv;
        __syncthreads();

        #pragma unroll
        for (int i = 0; i < (C_FEAT * CO_PPB) / CO_NTHREADS; ++i) {   // 8 stores
            const int idx = tid + CO_NTHREADS * i;
            const int c   = idx >> 7;                // channel
            const int lp  = idx & (CO_PPB - 1);      // point
            out[c * NPTS + p0 + lp] = s_out[lp][c];
        }
        __syncthreads();   // protect union before next chunk's phase 1
    }
}

// ======================= fallback two-kernel path (round 5) ==================
#define FB_PPB      64
#define FB_NTHREADS 512

__global__ __launch_bounds__(256) void uvt_prep(const float* __restrict__ in,
                                                const float* __restrict__ ego2cam,
                                                const float* __restrict__ cam2img,
                                                __half* __restrict__ featsT,
                                                float* __restrict__ projws) {
    const int blk = blockIdx.x;
    if (blk < NUM_CAMS * HF) {
        __shared__ float s[WF][C_FEAT + 1];
        const int n = blk / HF, y = blk % HF;
        const float* src = in + n * C_FEAT * HF * WF + y * WF;
        for (int e = threadIdx.x; e < C_FEAT * WF; e += 256) {
            const int c = e / WF, x = e - c * WF;
            s[x][c] = src[c * HF * WF + x];
        }
        __syncthreads();
        __half* dst = featsT + (n * HF + y) * WF * C_FEAT;
        for (int e = threadIdx.x; e < C_FEAT * WF; e += 256) {
            const int x = e >> 6, c = e & 63;
            dst[e] = __float2half(s[x][c]);
        }
    } else {
        const int t = threadIdx.x;
        if (t < NUM_CAMS * 12) {
            const int cam = t / 12, e = t - cam * 12;
            const int i = e >> 2, j = e & 3;
            const float* A = cam2img + cam * 16;
            const float* B = ego2cam + cam * 16;
            float sum = 0.f;
            #pragma unroll
            for (int k = 0; k < 4; ++k) sum += A[i*4 + k] * B[k*4 + j];
            projws[cam * 12 + e] = sum;
        }
    }
}

struct alignas(32) PC {
    __half2 w00, w10, w01, w11;
    int base, dx, dy, valid;
};

__global__ __launch_bounds__(FB_NTHREADS) void uvt_fuse(
    const __half* __restrict__ featsT,
    const float* __restrict__ projws,
    const float* __restrict__ vox,
    float* __restrict__ out)
{
    __shared__ PC    s_pc[NUM_CAMS][FB_PPB];
    __shared__ float s_out[FB_PPB][C_FEAT + 1];

    const int tid = threadIdx.x;
    const int p0  = blockIdx.x * FB_PPB;

    if (tid < NUM_CAMS * FB_PPB) {
        const int cam = __builtin_amdgcn_readfirstlane(tid >> 6);
        const int lp  = tid & 63;
        const int p   = p0 + lp;
        const float* M = projws + cam * 12;

        const float px = vox[p];
        const float py = vox[NPTS + p];
        const float pz = vox[2 * NPTS + p];
        const float ud = M[0]*px + M[1]*py + M[2]*pz  + M[3];
        const float vd = M[4]*px + M[5]*py + M[6]*pz  + M[7];
        const float d  = M[8]*px + M[9]*py + M[10]*pz + M[11];
        const float id = 1.0f / (d + 1e-6f);
        const float u  = ud * id;
        const float v  = vd * id;
        const bool valid = (d > 0.1f) && (u >= 0.f) && (u <= 703.f)
                                      && (v >= 0.f) && (v <= 255.f);
        PC pc;
        if (valid) {
            const float x  = u * 0.0625f;
            const float y  = v * 0.0625f;
            const float xf = floorf(x), yf = floorf(y);
            const int   x0 = (int)xf,   y0 = (int)yf;
            const float wx1 = x - xf,  wy1 = y - yf;
            const float wx0 = 1.f - wx1, wy0 = 1.f - wy1;
            const bool bx = (x0 < WF - 1);
            const bool by = (y0 < HF - 1);
            pc.w00 = __float2half2_rn(wx0 * wy0);
            pc.w10 = __float2half2_rn(bx ? wx1 * wy0 : 0.f);
            pc.w01 = __float2half2_rn(by ? wx0 * wy1 : 0.f);
            pc.w11 = __float2half2_rn((bx && by) ? wx1 * wy1 : 0.f);
            pc.base = ((cam * HF + y0) * WF + x0) << 6;
            pc.dx   = bx ? C_FEAT : 0;
            pc.dy   = by ? WF * C_FEAT : 0;
            pc.valid = 1;
        } else {
            pc.w00 = pc.w10 = pc.w01 = pc.w11 = __float2half2_rn(0.f);
            pc.base = pc.dx = pc.dy = 0;
            pc.valid = 0;
        }
        s_pc[cam][lp] = pc;
    }
    __syncthreads();

    const int oct = tid & 7;
    const int pl  = tid >> 3;
    int vm = 0, cnt = 0;
    #pragma unroll
    for (int cam = 0; cam < NUM_CAMS; ++cam) {
        const int v = s_pc[cam][pl].valid;
        vm |= v << cam;
        cnt += v;
    }
    const float inv = 1.0f / (float)(cnt > 0 ? cnt : 1);

    float2 a0 = {0.f,0.f}, a1 = {0.f,0.f}, a2 = {0.f,0.f}, a3 = {0.f,0.f};
    #pragma unroll
    for (int cam = 0; cam < NUM_CAMS; ++cam) {
        if ((vm >> cam) & 1) {
            const PC pc = s_pc[cam][pl];
            const __half* b = featsT + pc.base + (oct << 3);
            const uint4 r00 = *(const uint4*)(b);
            const uint4 r10 = *(const uint4*)(b + pc.dx);
            const uint4 r01 = *(const uint4*)(b + pc.dy);
            const uint4 r11 = *(const uint4*)(b + pc.dx + pc.dy);

            #define BC(u_) __builtin_bit_cast(__half2, u_)
            __half2 s0 = __hmul2(pc.w00, BC(r00.x));
            s0 = __hfma2(pc.w10, BC(r10.x), s0);
            s0 = __hfma2(pc.w01, BC(r01.x), s0);
            s0 = __hfma2(pc.w11, BC(r11.x), s0);
            __half2 s1 = __hmul2(pc.w00, BC(r00.y));
            s1 = __hfma2(pc.w10, BC(r10.y), s1);
            s1 = __hfma2(pc.w01, BC(r01.y), s1);
            s1 = __hfma2(pc.w11, BC(r11.y), s1);
            __half2 s2 = __hmul2(pc.w00, BC(r00.z));
            s2 = __hfma2(pc.w10, BC(r10.z), s2);
            s2 = __hfma2(pc.w01, BC(r01.z), s2);
            s2 = __hfma2(pc.w11, BC(r11.z), s2);
            __half2 s3 = __hmul2(pc.w00, BC(r00.w));
            s3 = __hfma2(pc.w10, BC(r10.w), s3);
            s3 = __hfma2(pc.w01, BC(r01.w), s3);
            s3 = __hfma2(pc.w11, BC(r11.w), s3);
            #undef BC

            const float2 f0 = __half22float2(s0);
            const float2 f1 = __half22float2(s1);
            const float2 f2 = __half22float2(s2);
            const float2 f3 = __half22float2(s3);
            a0.x += f0.x; a0.y += f0.y;
            a1.x += f1.x; a1.y += f1.y;
            a2.x += f2.x; a2.y += f2.y;
            a3.x += f3.x; a3.y += f3.y;
        }
    }

    const int cb = oct << 3;
    s_out[pl][cb + 0] = a0.x * inv;
    s_out[pl][cb + 1] = a0.y * inv;
    s_out[pl][cb + 2] = a1.x * inv;
    s_out[pl][cb + 3] = a1.y * inv;
    s_out[pl][cb + 4] = a2.x * inv;
    s_out[pl][cb + 5] = a2.y * inv;
    s_out[pl][cb + 6] = a3.x * inv;
    s_out[pl][cb + 7] = a3.y * inv;
    __syncthreads();

    #pragma unroll
    for (int i = 0; i < 8; ++i) {
        const int idx = tid + FB_NTHREADS * i;
        const int c   = idx >> 6;
        const int lp  = idx & 63;
        out[c * NPTS + p0 + lp] = s_out[lp][c];
    }
}

// ---------------------------------------------------------------------------
extern "C" void kernel_launch(void* const* d_in, const int* in_sizes, int n_in,
                              void* d_out, int out_size, void* d_ws, size_t ws_size,
                              hipStream_t stream) {
    const float* img_feats = (const float*)d_in[0];  // (6,64,16,44)
    const float* ego2cam   = (const float*)d_in[1];  // (6,4,4)
    const float* cam2img   = (const float*)d_in[2];  // (6,4,4)
    const float* vox       = (const float*)d_in[3];  // (3,8,128,128)
    float* out = (float*)d_out;                      // (1,64,8,128,128)

    __half* featsT = (__half*)d_ws;                  // 270336 halves
    float*  projws = (float*)((char*)d_ws + FEAT_ELEMS * sizeof(__half)); // 72 floats

    // Static precheck: can 256 blocks of 1024 threads be co-resident?
    int blocksPerCU = 0;
    hipError_t qerr = hipOccupancyMaxActiveBlocksPerMultiprocessor(
        &blocksPerCU, (const void*)uvt_all, CO_NTHREADS, 0);

    bool coop_ok = (qerr == hipSuccess) && (blocksPerCU >= 1);
    if (coop_ok) {
        void* args[] = {(void*)&img_feats, (void*)&ego2cam, (void*)&cam2img,
                        (void*)&vox, (void*)&featsT, (void*)&projws, (void*)&out};
        hipError_t lerr = hipLaunchCooperativeKernel((const void*)uvt_all,
                                                     dim3(CO_NBLOCKS), dim3(CO_NTHREADS),
                                                     args, 0, stream);
        if (lerr == hipSuccess) return;
    }

    // Fallback: proven two-kernel path
    uvt_prep<<<NUM_CAMS * HF + 1, 256, 0, stream>>>(img_feats, ego2cam, cam2img,
                                                    featsT, projws);
    uvt_fuse<<<NPTS / FB_PPB, FB_NTHREADS, 0, stream>>>(featsT, projws, vox, out);
}

// Round 9
// 19.956 us; speedup vs baseline: 5.7363x; 5.7363x over previous
//
#include <hip/hip_runtime.h>
#include <hip/hip_fp16.h>

#define NUM_CAMS 6
#define C_FEAT   64
#define HF       16
#define WF       44
#define NPTS     (128*128*8)   // 131072
#define FEAT_ELEMS (NUM_CAMS*C_FEAT*HF*WF)  // 270336
#define PPB      64            // points per block
#define NTHREADS 512

// ---- kernel 1: flat transpose+fp16 convert (full grid) + proj matmul ----
__global__ __launch_bounds__(256) void uvt_prep(const float* __restrict__ in,
                                                const float* __restrict__ ego2cam,
                                                const float* __restrict__ cam2img,
                                                __half* __restrict__ featsT,
                                                float* __restrict__ projws) {
    const int blk = blockIdx.x;
    if (blk < FEAT_ELEMS / 256) {
        const int g   = blk * 256 + threadIdx.x;
        const int c   = g & 63;
        const int pix = g >> 6;
        const int x   = pix % WF;
        const int t2  = pix / WF;
        const int y   = t2 % HF;
        const int n   = t2 / HF;
        featsT[g] = __float2half(in[((n * C_FEAT + c) * HF + y) * WF + x]);
    } else {
        const int t = threadIdx.x;
        if (t < NUM_CAMS * 12) {
            const int cam = t / 12, e = t - cam * 12;
            const int i = e >> 2, j = e & 3;
            const float* A = cam2img + cam * 16;
            const float* B = ego2cam + cam * 16;
            float sum = 0.f;
            #pragma unroll
            for (int k = 0; k < 4; ++k) sum += A[i*4 + k] * B[k*4 + j];
            projws[cam * 12 + e] = sum;
        }
    }
}

// packed per (point,cam) sampling params: 16 B -> one ds_read_b128
struct alignas(16) PCP {
    __half2  wA;     // {w00, w10}
    __half2  wB;     // {w01, w11}
    int      base;   // half-elem offset of (cam,y0,x0) pixel
    unsigned flags;  // dx | (dy<<16) | (valid<<31)
};

// ---- kernel 2: project + packed-half bilinear + fuse, LDS-coalesced stores ----
// 512 threads = 64 points x 8 channel-octs; oct = tid&7 (16B), pl = tid>>3
__global__ __launch_bounds__(NTHREADS) void uvt_fuse(
    const __half* __restrict__ featsT,  // (6,16,44,64) fp16
    const float* __restrict__ projws,   // (6,3,4)
    const float* __restrict__ vox,      // (3, NPTS)
    float* __restrict__ out)            // (64, NPTS)
{
    // LDS union: s_pc (6 KB) lives inside s_out's 16.6 KB footprint
    __shared__ __align__(16) char ldsbuf[PPB * (C_FEAT + 1) * sizeof(float)];
    PCP   (*s_pc)[PPB]         = (PCP (*)[PPB])ldsbuf;
    float (*s_out)[C_FEAT + 1] = (float (*)[C_FEAT + 1])ldsbuf;

    const int tid = threadIdx.x;
    const int p0  = blockIdx.x * PPB;

    // ---- phase 1: per (point,cam) params; one cam per wave -> scalar proj ----
    if (tid < NUM_CAMS * PPB) {         // 384 threads, 6 waves
        const int cam = __builtin_amdgcn_readfirstlane(tid >> 6);
        const int lp  = tid & 63;
        const int p   = p0 + lp;
        const float* M = projws + cam * 12;

        const float px = vox[p];
        const float py = vox[NPTS + p];
        const float pz = vox[2 * NPTS + p];
        const float ud = M[0]*px + M[1]*py + M[2]*pz  + M[3];
        const float vd = M[4]*px + M[5]*py + M[6]*pz  + M[7];
        const float d  = M[8]*px + M[9]*py + M[10]*pz + M[11];
        const float id = 1.0f / (d + 1e-6f);
        const float u  = ud * id;
        const float v  = vd * id;
        const bool valid = (d > 0.1f) && (u >= 0.f) && (u <= 703.f)
                                      && (v >= 0.f) && (v <= 255.f);
        PCP pc;
        if (valid) {
            const float x  = u * 0.0625f;
            const float y  = v * 0.0625f;
            const float xf = floorf(x), yf = floorf(y);
            const int   x0 = (int)xf,   y0 = (int)yf;
            const float wx1 = x - xf,  wy1 = y - yf;
            const float wx0 = 1.f - wx1, wy0 = 1.f - wy1;
            const bool bx = (x0 < WF - 1);
            const bool by = (y0 < HF - 1);
            pc.wA = __halves2half2(__float2half(wx0 * wy0),
                                   __float2half(bx ? wx1 * wy0 : 0.f));
            pc.wB = __halves2half2(__float2half(by ? wx0 * wy1 : 0.f),
                                   __float2half((bx && by) ? wx1 * wy1 : 0.f));
            pc.base  = ((cam * HF + y0) * WF + x0) << 6;
            pc.flags = (bx ? 64u : 0u)
                     | ((by ? (unsigned)(WF * C_FEAT) : 0u) << 16)
                     | 0x80000000u;
        } else {
            pc.wA = pc.wB = __halves2half2(__float2half(0.f), __float2half(0.f));
            pc.base = 0; pc.flags = 0u;
        }
        s_pc[cam][lp] = pc;          // one ds_write_b128
    }
    __syncthreads();

    // ---- phase 2: vmask + gated packed-half gather ----
    const int oct = tid & 7;
    const int pl  = tid >> 3;
    float2 a0 = {0.f,0.f}, a1 = {0.f,0.f}, a2 = {0.f,0.f}, a3 = {0.f,0.f};
    int cnt = 0;

    #pragma unroll
    for (int cam = 0; cam < NUM_CAMS; ++cam) {
        const PCP pc = s_pc[cam][pl];          // one ds_read_b128
        const unsigned fl = pc.flags;
        cnt += (int)(fl >> 31);
        if (fl >> 31) {                        // exec-masked
            const int dx = (int)(fl & 0xFFFFu);
            const int dy = (int)((fl >> 16) & 0x7FFFu);
            const __half* b = featsT + pc.base + (oct << 3);
            const uint4 r00 = *(const uint4*)(b);
            const uint4 r10 = *(const uint4*)(b + dx);
            const uint4 r01 = *(const uint4*)(b + dy);
            const uint4 r11 = *(const uint4*)(b + dx + dy);

            const __half2 w00 = __low2half2(pc.wA);
            const __half2 w10 = __high2half2(pc.wA);
            const __half2 w01 = __low2half2(pc.wB);
            const __half2 w11 = __high2half2(pc.wB);
            #define BC(u_) __builtin_bit_cast(__half2, u_)
            __half2 s0 = __hmul2(w00, BC(r00.x));
            s0 = __hfma2(w10, BC(r10.x), s0);
            s0 = __hfma2(w01, BC(r01.x), s0);
            s0 = __hfma2(w11, BC(r11.x), s0);
            __half2 s1 = __hmul2(w00, BC(r00.y));
            s1 = __hfma2(w10, BC(r10.y), s1);
            s1 = __hfma2(w01, BC(r01.y), s1);
            s1 = __hfma2(w11, BC(r11.y), s1);
            __half2 s2 = __hmul2(w00, BC(r00.z));
            s2 = __hfma2(w10, BC(r10.z), s2);
            s2 = __hfma2(w01, BC(r01.z), s2);
            s2 = __hfma2(w11, BC(r11.z), s2);
            __half2 s3 = __hmul2(w00, BC(r00.w));
            s3 = __hfma2(w10, BC(r10.w), s3);
            s3 = __hfma2(w01, BC(r01.w), s3);
            s3 = __hfma2(w11, BC(r11.w), s3);
            #undef BC

            const float2 f0 = __half22float2(s0);
            const float2 f1 = __half22float2(s1);
            const float2 f2 = __half22float2(s2);
            const float2 f3 = __half22float2(s3);
            a0.x += f0.x; a0.y += f0.y;
            a1.x += f1.x; a1.y += f1.y;
            a2.x += f2.x; a2.y += f2.y;
            a3.x += f3.x; a3.y += f3.y;
        }
    }
    __syncthreads();   // all s_pc reads done before s_out overwrites union

    // ---- phase 3: transpose through LDS, 256 B-coalesced stores ----
    const float inv = 1.0f / (float)(cnt > 0 ? cnt : 1);
    const int cb = oct << 3;
    s_out[pl][cb + 0] = a0.x * inv;
    s_out[pl][cb + 1] = a0.y * inv;
    s_out[pl][cb + 2] = a1.x * inv;
    s_out[pl][cb + 3] = a1.y * inv;
    s_out[pl][cb + 4] = a2.x * inv;
    s_out[pl][cb + 5] = a2.y * inv;
    s_out[pl][cb + 6] = a3.x * inv;
    s_out[pl][cb + 7] = a3.y * inv;
    __syncthreads();

    #pragma unroll
    for (int i = 0; i < 8; ++i) {
        const int idx = tid + NTHREADS * i;   // 0..4095
        const int c   = idx >> 6;             // channel
        const int lp  = idx & 63;             // point (64 consecutive per wave)
        out[c * NPTS + p0 + lp] = s_out[lp][c];
    }
}

// ---------------------------------------------------------------------------
extern "C" void kernel_launch(void* const* d_in, const int* in_sizes, int n_in,
                              void* d_out, int out_size, void* d_ws, size_t ws_size,
                              hipStream_t stream) {
    const float* img_feats = (const float*)d_in[0];  // (6,64,16,44)
    const float* ego2cam   = (const float*)d_in[1];  // (6,4,4)
    const float* cam2img   = (const float*)d_in[2];  // (6,4,4)
    const float* vox       = (const float*)d_in[3];  // (3,8,128,128)
    float* out = (float*)d_out;                      // (1,64,8,128,128)

    __half* featsT = (__half*)d_ws;                  // 270336 halves
    float*  projws = (float*)((char*)d_ws + FEAT_ELEMS * sizeof(__half)); // 72 floats

    uvt_prep<<<FEAT_ELEMS / 256 + 1, 256, 0, stream>>>(img_feats, ego2cam, cam2img,
                                                       featsT, projws);
    uvt_fuse<<<NPTS / PPB, NTHREADS, 0, stream>>>(featsT, projws, vox, out);
}